// Round 1
// baseline (596.911 us; speedup 1.0000x reference)
//
#include <hip/hip_runtime.h>
#include <hip/hip_bf16.h>

// Problem constants
#define BB 8
#define NN 1024
#define CC 544      // J*F = 17*32
#define JJ 17
#define FF 32
#define HH 8
#define HD 68
#define BN 8192     // B*N
#define KD 544      // GEMM K dim (=C)
#define NCQ 1632    // 3*C
#define NCQP 1664   // padded to 13*128
#define NCPP 640    // proj out padded to 5*128

using f32x4  = __attribute__((ext_vector_type(4))) float;
using bf16x8 = __attribute__((ext_vector_type(8))) short;

__device__ __forceinline__ void gld_lds16(const void* g, void* l) {
  __builtin_amdgcn_global_load_lds(
      (const __attribute__((address_space(1))) void*)g,
      (__attribute__((address_space(3))) void*)l, 16, 0, 0);
}

// ---------------------------------------------------------------- K0: weights -> bf16 (padded)
__global__ __launch_bounds__(256) void wconv(const float* __restrict__ qkv_w,
                                             const float* __restrict__ proj_w,
                                             __hip_bfloat16* __restrict__ qw,
                                             __hip_bfloat16* __restrict__ pw) {
  int idx = blockIdx.x * 256 + threadIdx.x;
  const int t1 = NCQP * KD;
  if (idx < t1) {
    int r = idx / KD;
    qw[idx] = __float2bfloat16(r < NCQ ? qkv_w[idx] : 0.f);
  } else {
    int k = idx - t1;
    if (k < NCPP * KD) {
      int r = k / KD;
      pw[k] = __float2bfloat16(r < CC ? proj_w[k] : 0.f);
    }
  }
}

// ---------------------------------------------------------------- K1: per-joint LN + attention-pool scores
__global__ __launch_bounds__(64) void ln1_scores(const float* __restrict__ x,
                                                 const float* __restrict__ g,
                                                 const float* __restrict__ bta,
                                                 const float* __restrict__ apw,
                                                 const float* __restrict__ apb,
                                                 float* __restrict__ xr,
                                                 float* __restrict__ scores) {
  int bn = blockIdx.x, lane = threadIdx.x;
  int f = lane & 31, half = lane >> 5;
  const float* row = x + (size_t)bn * CC;
  float gg = g[f], bb = bta[f], aw = apw[f], ab = apb[0];
  for (int it = 0; it < 9; ++it) {
    int j = it * 2 + half;
    bool act = (j < JJ);
    float v = act ? row[j * FF + f] : 0.f;
    float s = v;
    for (int m = 16; m >= 1; m >>= 1) s += __shfl_xor(s, m);
    float mu = s * (1.f / 32.f);
    float dv = v - mu;
    float s2 = dv * dv;
    for (int m = 16; m >= 1; m >>= 1) s2 += __shfl_xor(s2, m);
    float xn = dv * rsqrtf(s2 * (1.f / 32.f) + 1e-5f) * gg + bb;
    float sc = xn * aw;
    for (int m = 16; m >= 1; m >>= 1) sc += __shfl_xor(sc, m);
    if (act) {
      xr[(size_t)bn * CC + j * FF + f] = xn;
      if (f == 0) scores[bn * JJ + j] = sc + ab;
    }
  }
}

// ---------------------------------------------------------------- K2: softmax over sequence axis N per (b,j)
__global__ __launch_bounds__(256) void softmax_n(const float* __restrict__ scores,
                                                 float* __restrict__ wsm) {
  int bj = blockIdx.x;
  int b = bj / JJ, j = bj - b * JJ;
  const float* s = scores + (size_t)b * NN * JJ + j;
  float* wp = wsm + (size_t)b * NN * JJ + j;
  int t = threadIdx.x;
  float v[4];
  float mx = -1e30f;
#pragma unroll
  for (int i = 0; i < 4; ++i) { v[i] = s[(t + 256 * i) * JJ]; mx = fmaxf(mx, v[i]); }
#pragma unroll
  for (int m = 32; m >= 1; m >>= 1) mx = fmaxf(mx, __shfl_xor(mx, m));
  __shared__ float red[4];
  if ((t & 63) == 0) red[t >> 6] = mx;
  __syncthreads();
  mx = fmaxf(fmaxf(red[0], red[1]), fmaxf(red[2], red[3]));
  float sum = 0.f;
#pragma unroll
  for (int i = 0; i < 4; ++i) { v[i] = __expf(v[i] - mx); sum += v[i]; }
#pragma unroll
  for (int m = 32; m >= 1; m >>= 1) sum += __shfl_xor(sum, m);
  __shared__ float red2[4];
  if ((t & 63) == 0) red2[t >> 6] = sum;
  __syncthreads();
  sum = red2[0] + red2[1] + red2[2] + red2[3];
  float inv = 1.f / sum;
#pragma unroll
  for (int i = 0; i < 4; ++i) wp[(t + 256 * i) * JJ] = v[i] * inv;
}

// ---------------------------------------------------------------- K3: xp = xr*w, LN2 over C, -> bf16
__global__ __launch_bounds__(64) void ln2_xp(const float* __restrict__ xr,
                                             const float* __restrict__ wsm,
                                             const float* __restrict__ g2,
                                             const float* __restrict__ b2,
                                             __hip_bfloat16* __restrict__ xp) {
  int bn = blockIdx.x, lane = threadIdx.x;
  __shared__ float wsh[JJ];
  if (lane < JJ) wsh[lane] = wsm[bn * JJ + lane];
  __syncthreads();
  float vals[9];
  float sum = 0.f;
  for (int it = 0; it < 9; ++it) {
    int c = it * 64 + lane;
    float v = 0.f;
    if (c < CC) v = xr[(size_t)bn * CC + c] * wsh[c >> 5];
    vals[it] = v;
    sum += v;
  }
  for (int m = 32; m >= 1; m >>= 1) sum += __shfl_xor(sum, m);
  float mu = sum * (1.f / 544.f);
  float s2 = 0.f;
  for (int it = 0; it < 9; ++it) {
    int c = it * 64 + lane;
    if (c < CC) { float dv = vals[it] - mu; s2 += dv * dv; }
  }
  for (int m = 32; m >= 1; m >>= 1) s2 += __shfl_xor(s2, m);
  float rstd = rsqrtf(s2 * (1.f / 544.f) + 1e-5f);
  for (int it = 0; it < 9; ++it) {
    int c = it * 64 + lane;
    if (c < CC)
      xp[(size_t)bn * CC + c] = __float2bfloat16((vals[it] - mu) * rstd * g2[c] + b2[c]);
  }
}

// ---------------------------------------------------------------- GEMM: C[M,N] = A[M,K] * B[N,K]^T, bf16 MFMA
// MODE 0: qkv — q,k stored to qkv[8192][1632]; v stored transposed to vt[B,H,68,1024]
// MODE 1: proj — fp32 + bias to out[8192][544]
template <int MODE>
__global__ __launch_bounds__(256) void gemm_nt(const __hip_bfloat16* __restrict__ A,
                                               const __hip_bfloat16* __restrict__ Bw,
                                               __hip_bfloat16* __restrict__ Cq,
                                               __hip_bfloat16* __restrict__ Vt,
                                               float* __restrict__ Cf,
                                               const float* __restrict__ bias) {
  __shared__ __hip_bfloat16 As[128 * 32];
  __shared__ __hip_bfloat16 Bs[128 * 32];
  const int t = threadIdx.x;
  const int w = t >> 6, lane = t & 63;
  const int fr = lane & 15, fq = lane >> 4;
  const int m0 = blockIdx.x * 128;
  const int n0 = blockIdx.y * 128;
  const int wm = (w >> 1) * 64, wn = (w & 1) * 64;

  f32x4 acc[4][4] = {};

  const __hip_bfloat16* Ag = A + (size_t)m0 * KD;
  const __hip_bfloat16* Bg = Bw + (size_t)n0 * KD;

  for (int kt = 0; kt < 17; ++kt) {
    const int k0 = kt * 32;
#pragma unroll
    for (int i = 0; i < 2; ++i) {
      int cb = (i * 4 + w) * 64;  // wave-uniform chunk base
      int chunk = cb + lane;
      int row = chunk >> 2, c16 = chunk & 3;
      gld_lds16(Ag + (size_t)row * KD + k0 + c16 * 8, &As[cb * 8]);
      gld_lds16(Bg + (size_t)row * KD + k0 + c16 * 8, &Bs[cb * 8]);
    }
    __syncthreads();
    bf16x8 af[4], bfr[4];
#pragma unroll
    for (int tm = 0; tm < 4; ++tm)
      af[tm] = *(const bf16x8*)&As[(wm + tm * 16 + fr) * 32 + fq * 8];
#pragma unroll
    for (int tn = 0; tn < 4; ++tn)
      bfr[tn] = *(const bf16x8*)&Bs[(wn + tn * 16 + fr) * 32 + fq * 8];
#pragma unroll
    for (int tm = 0; tm < 4; ++tm)
#pragma unroll
      for (int tn = 0; tn < 4; ++tn)
        acc[tm][tn] = __builtin_amdgcn_mfma_f32_16x16x32_bf16(af[tm], bfr[tn], acc[tm][tn], 0, 0, 0);
    __syncthreads();
  }

  if (MODE == 1) {
#pragma unroll
    for (int tn = 0; tn < 4; ++tn) {
      int o = n0 + wn + tn * 16 + fr;
      if (o < CC) {
        float bb = bias[o];
#pragma unroll
        for (int tm = 0; tm < 4; ++tm) {
          int m = m0 + wm + tm * 16 + fq * 4;
#pragma unroll
          for (int r = 0; r < 4; ++r)
            Cf[(size_t)(m + r) * CC + o] = acc[tm][tn][r] + bb;
        }
      }
    }
  } else {
    int b = m0 >> 10;
#pragma unroll
    for (int tn = 0; tn < 4; ++tn) {
      int o = n0 + wn + tn * 16 + fr;
      if (o < 2 * CC) {  // q or k
#pragma unroll
        for (int tm = 0; tm < 4; ++tm) {
          int m = m0 + wm + tm * 16 + fq * 4;
#pragma unroll
          for (int r = 0; r < 4; ++r)
            Cq[(size_t)(m + r) * NCQ + o] = __float2bfloat16(acc[tm][tn][r]);
        }
      } else if (o < NCQ) {  // v -> transposed
        int oo = o - 2 * CC;
        int h = oo / HD;
        int d = oo - h * HD;
        __hip_bfloat16* vrow = Vt + (((size_t)b * HH + h) * HD + d) * NN;
#pragma unroll
        for (int tm = 0; tm < 4; ++tm) {
          int m = m0 + wm + tm * 16 + fq * 4;
          int n = m & (NN - 1);
#pragma unroll
          for (int r = 0; r < 4; ++r)
            vrow[n + r] = __float2bfloat16(acc[tm][tn][r]);
        }
      }
    }
  }
}

// ---------------------------------------------------------------- Flash attention, bf16 MFMA
// grid (16 qtiles, H, B), 256 threads = 4 waves x 16 q-rows
__global__ __launch_bounds__(256) void attn_kernel(const __hip_bfloat16* __restrict__ qkv,
                                                   const __hip_bfloat16* __restrict__ Vt,
                                                   const float* __restrict__ sfp,
                                                   __hip_bfloat16* __restrict__ Ao) {
  __shared__ __hip_bfloat16 Qs[64][104];   // 64 q-rows x (hd padded 96, row-stride 104 for banks)
  __shared__ __hip_bfloat16 Ks[64][104];
  __shared__ __hip_bfloat16 Vs[80][72];    // V^T: d-rows x 64 keys (stride 72)
  __shared__ __hip_bfloat16 Ps[4][16][72]; // per-wave P round-trip (C-layout -> A-layout)
  const int t = threadIdx.x;
  const int w = t >> 6, lane = t & 63;
  const int fr = lane & 15, fq = lane >> 4;
  const int qt = blockIdx.x, h = blockIdx.y, b = blockIdx.z;
  const int q0 = qt * 64;
  const float sf = sfp[0];
  const float scale = 0.12126781251816650f;  // 68^-0.5

  const __hip_bfloat16* qbase = qkv + (size_t)(b * NN + q0) * NCQ + h * HD;
  for (int idx = t; idx < 64 * 96; idx += 256) {
    int r = idx / 96, d = idx - r * 96;
    Qs[r][d] = (d < HD) ? qbase[(size_t)r * NCQ + d] : __float2bfloat16(0.f);
  }
  __syncthreads();
  bf16x8 qa[3];
#pragma unroll
  for (int ks = 0; ks < 3; ++ks)
    qa[ks] = *(const bf16x8*)&Qs[w * 16 + fr][ks * 32 + fq * 8];

  f32x4 o_acc[5] = {};
  float m_i[4], l_i[4];
#pragma unroll
  for (int r = 0; r < 4; ++r) { m_i[r] = -1e30f; l_i[r] = 0.f; }

  const __hip_bfloat16* kbase = qkv + (size_t)b * NN * NCQ + CC + h * HD;
  const __hip_bfloat16* vbase = Vt + ((size_t)b * HH + h) * HD * NN;

  for (int kt = 0; kt < 16; ++kt) {
    __syncthreads();  // all waves done reading previous K/V tiles
    for (int idx = t; idx < 64 * 96; idx += 256) {
      int r = idx / 96, d = idx - r * 96;
      Ks[r][d] = (d < HD) ? kbase[(size_t)(kt * 64 + r) * NCQ + d] : __float2bfloat16(0.f);
    }
    for (int idx = t; idx < 80 * 64; idx += 256) {
      int d = idx >> 6, kk = idx & 63;
      Vs[d][kk] = (d < HD) ? vbase[(size_t)d * NN + kt * 64 + kk] : __float2bfloat16(0.f);
    }
    __syncthreads();

    // S = Q K^T  (16q x 64k per wave)
    f32x4 s[4] = {};
#pragma unroll
    for (int tn = 0; tn < 4; ++tn) {
#pragma unroll
      for (int ks = 0; ks < 3; ++ks) {
        bf16x8 kb = *(const bf16x8*)&Ks[tn * 16 + fr][ks * 32 + fq * 8];
        s[tn] = __builtin_amdgcn_mfma_f32_16x16x32_bf16(qa[ks], kb, s[tn], 0, 0, 0);
      }
    }
    // logit scaling: scale * pos_scale[key]
#pragma unroll
    for (int tn = 0; tn < 4; ++tn) {
      int key = kt * 64 + tn * 16 + fr;
      float pos = key * (1.f / 1023.f) - 0.5f;
      float ps = __expf(-sf * pos * pos) * scale;
#pragma unroll
      for (int r = 0; r < 4; ++r) s[tn][r] *= ps;
    }
    // online softmax (rows = fq*4+r, cols across fr within quad)
    float alpha[4];
#pragma unroll
    for (int r = 0; r < 4; ++r) {
      float mx = fmaxf(fmaxf(s[0][r], s[1][r]), fmaxf(s[2][r], s[3][r]));
#pragma unroll
      for (int msk = 8; msk >= 1; msk >>= 1) mx = fmaxf(mx, __shfl_xor(mx, msk));
      float mn = fmaxf(m_i[r], mx);
      alpha[r] = __expf(m_i[r] - mn);
      m_i[r] = mn;
      float rs = 0.f;
#pragma unroll
      for (int tn = 0; tn < 4; ++tn) {
        float p = __expf(s[tn][r] - mn);
        s[tn][r] = p;
        rs += p;
      }
#pragma unroll
      for (int msk = 8; msk >= 1; msk >>= 1) rs += __shfl_xor(rs, msk);
      l_i[r] = l_i[r] * alpha[r] + rs;
#pragma unroll
      for (int tv = 0; tv < 5; ++tv) o_acc[tv][r] *= alpha[r];
    }
    // P: C-layout -> LDS -> A-layout
#pragma unroll
    for (int tn = 0; tn < 4; ++tn)
#pragma unroll
      for (int r = 0; r < 4; ++r)
        Ps[w][fq * 4 + r][tn * 16 + fr] = __float2bfloat16(s[tn][r]);
    // O += P V
#pragma unroll
    for (int ks2 = 0; ks2 < 2; ++ks2) {
      bf16x8 pa = *(const bf16x8*)&Ps[w][fr][ks2 * 32 + fq * 8];
#pragma unroll
      for (int tv = 0; tv < 5; ++tv) {
        bf16x8 vb = *(const bf16x8*)&Vs[tv * 16 + fr][ks2 * 32 + fq * 8];
        o_acc[tv] = __builtin_amdgcn_mfma_f32_16x16x32_bf16(pa, vb, o_acc[tv], 0, 0, 0);
      }
    }
  }
  // epilogue: O / l -> bf16 attn_out[m][h*68+d]
  __hip_bfloat16* obase = Ao + (size_t)(b * NN + q0 + w * 16) * CC + h * HD;
  float inv[4];
#pragma unroll
  for (int r = 0; r < 4; ++r) inv[r] = 1.f / l_i[r];
#pragma unroll
  for (int tv = 0; tv < 5; ++tv) {
    int d = tv * 16 + fr;
    if (d < HD) {
#pragma unroll
      for (int r = 0; r < 4; ++r)
        obase[(size_t)(fq * 4 + r) * CC + d] = __float2bfloat16(o_acc[tv][r] * inv[r]);
    }
  }
}

// ---------------------------------------------------------------- launch
extern "C" void kernel_launch(void* const* d_in, const int* in_sizes, int n_in,
                              void* d_out, int out_size, void* d_ws, size_t ws_size,
                              hipStream_t stream) {
  (void)in_sizes; (void)n_in; (void)out_size; (void)ws_size;
  const float* x       = (const float*)d_in[0];
  const float* norm_g  = (const float*)d_in[1];
  const float* norm_b  = (const float*)d_in[2];
  const float* ap_w    = (const float*)d_in[3];
  const float* ap_b    = (const float*)d_in[4];
  const float* norm2_g = (const float*)d_in[5];
  const float* norm2_b = (const float*)d_in[6];
  const float* qkv_w   = (const float*)d_in[7];
  const float* proj_w  = (const float*)d_in[8];
  const float* proj_b  = (const float*)d_in[9];
  const float* sf      = (const float*)d_in[10];
  float* out = (float*)d_out;
  char* ws = (char*)d_ws;

  // workspace layout (bytes)
  float* xr              = (float*)(ws);                       // 8192*544*4  = 17825792
  float* scores          = (float*)(ws + 17825792);            // 8192*17*4   = 557056
  float* wsm             = (float*)(ws + 18382848);            // 557056
  __hip_bfloat16* xp     = (__hip_bfloat16*)(ws + 18939904);   // 8192*544*2  = 8912896
  __hip_bfloat16* qw     = (__hip_bfloat16*)(ws + 27852800);   // 1664*544*2  = 1810432
  __hip_bfloat16* pw     = (__hip_bfloat16*)(ws + 29663232);   // 640*544*2   = 696320
  __hip_bfloat16* qkv    = (__hip_bfloat16*)(ws + 30359552);   // 8192*1632*2 = 26738688
  __hip_bfloat16* vt     = (__hip_bfloat16*)(ws + 57098240);   // 8*8*68*1024*2 = 8912896
  __hip_bfloat16* ao     = (__hip_bfloat16*)(ws + 66011136);   // 8192*544*2  = 8912896
  // total 74924032 bytes

  wconv<<<4896, 256, 0, stream>>>(qkv_w, proj_w, qw, pw);
  ln1_scores<<<BN, 64, 0, stream>>>(x, norm_g, norm_b, ap_w, ap_b, xr, scores);
  softmax_n<<<BB * JJ, 256, 0, stream>>>(scores, wsm);
  ln2_xp<<<BN, 64, 0, stream>>>(xr, wsm, norm2_g, norm2_b, xp);
  gemm_nt<0><<<dim3(64, 13), 256, 0, stream>>>(xp, qw, qkv, vt, nullptr, nullptr);
  attn_kernel<<<dim3(16, HH, BB), 256, 0, stream>>>(qkv, vt, sf, ao);
  gemm_nt<1><<<dim3(64, 5), 256, 0, stream>>>(ao, pw, nullptr, nullptr, out, proj_b);
}

// Round 3
// 269.671 us; speedup vs baseline: 2.2135x; 2.2135x over previous
//
#include <hip/hip_runtime.h>
#include <hip/hip_bf16.h>

// Problem constants
#define BB 8
#define NN 1024
#define CC 544      // J*F = 17*32
#define JJ 17
#define FF 32
#define HH 8
#define HD 68
#define BN 8192     // B*N
#define KD 544      // GEMM K dim (=C)
#define NCQ 1632    // 3*C
#define NCQP 1664   // padded to 13*128
#define NCPP 640    // proj out padded to 5*128
#define HDP 96      // head dim padded for QK (3x K=32)

using f32x4  = __attribute__((ext_vector_type(4))) float;
using bf16x8 = __attribute__((ext_vector_type(8))) short;

__device__ __forceinline__ void gld_lds16(const void* g, void* l) {
  __builtin_amdgcn_global_load_lds(
      (const __attribute__((address_space(1))) void*)g,
      (__attribute__((address_space(3))) void*)l, 16, 0, 0);
}

// ---------------------------------------------------------------- K0: weights -> bf16 (padded)
__global__ __launch_bounds__(256) void wconv(const float* __restrict__ qkv_w,
                                             const float* __restrict__ proj_w,
                                             __hip_bfloat16* __restrict__ qw,
                                             __hip_bfloat16* __restrict__ pw) {
  int idx = blockIdx.x * 256 + threadIdx.x;
  const int t1 = NCQP * KD;
  if (idx < t1) {
    int r = idx / KD;
    qw[idx] = __float2bfloat16(r < NCQ ? qkv_w[idx] : 0.f);
  } else {
    int k = idx - t1;
    if (k < NCPP * KD) {
      int r = k / KD;
      pw[k] = __float2bfloat16(r < CC ? proj_w[k] : 0.f);
    }
  }
}

// ---------------------------------------------------------------- K0b: zero pad cols 68..95 of Qp||Kp
// Qp,Kp contiguous: 2*8*8*1024 = 131072 rows of 96 elems; pad = 28 elems = 56B at byte 136
__global__ __launch_bounds__(256) void zero_qk_pad(char* __restrict__ qkp) {
  int t = blockIdx.x * 256 + threadIdx.x;  // 131072*7 = 917504 tasks
  if (t < 131072 * 7) {
    int row = t / 7, i = t - row * 7;
    *(unsigned long long*)(qkp + (size_t)row * 192 + 136 + i * 8) = 0ull;
  }
}

// ---------------------------------------------------------------- K1: per-joint LN + attention-pool scores
__global__ __launch_bounds__(64) void ln1_scores(const float* __restrict__ x,
                                                 const float* __restrict__ g,
                                                 const float* __restrict__ bta,
                                                 const float* __restrict__ apw,
                                                 const float* __restrict__ apb,
                                                 float* __restrict__ xr,
                                                 float* __restrict__ scores) {
  int bn = blockIdx.x, lane = threadIdx.x;
  int f = lane & 31, half = lane >> 5;
  const float* row = x + (size_t)bn * CC;
  float gg = g[f], bb = bta[f], aw = apw[f], ab = apb[0];
  for (int it = 0; it < 9; ++it) {
    int j = it * 2 + half;
    bool act = (j < JJ);
    float v = act ? row[j * FF + f] : 0.f;
    float s = v;
    for (int m = 16; m >= 1; m >>= 1) s += __shfl_xor(s, m);
    float mu = s * (1.f / 32.f);
    float dv = v - mu;
    float s2 = dv * dv;
    for (int m = 16; m >= 1; m >>= 1) s2 += __shfl_xor(s2, m);
    float xn = dv * rsqrtf(s2 * (1.f / 32.f) + 1e-5f) * gg + bb;
    float sc = xn * aw;
    for (int m = 16; m >= 1; m >>= 1) sc += __shfl_xor(sc, m);
    if (act) {
      xr[(size_t)bn * CC + j * FF + f] = xn;
      if (f == 0) scores[bn * JJ + j] = sc + ab;
    }
  }
}

// ---------------------------------------------------------------- K2: softmax over sequence axis N per (b,j)
__global__ __launch_bounds__(256) void softmax_n(const float* __restrict__ scores,
                                                 float* __restrict__ wsm) {
  int bj = blockIdx.x;
  int b = bj / JJ, j = bj - b * JJ;
  const float* s = scores + (size_t)b * NN * JJ + j;
  float* wp = wsm + (size_t)b * NN * JJ + j;
  int t = threadIdx.x;
  float v[4];
  float mx = -1e30f;
#pragma unroll
  for (int i = 0; i < 4; ++i) { v[i] = s[(t + 256 * i) * JJ]; mx = fmaxf(mx, v[i]); }
#pragma unroll
  for (int m = 32; m >= 1; m >>= 1) mx = fmaxf(mx, __shfl_xor(mx, m));
  __shared__ float red[4];
  if ((t & 63) == 0) red[t >> 6] = mx;
  __syncthreads();
  mx = fmaxf(fmaxf(red[0], red[1]), fmaxf(red[2], red[3]));
  float sum = 0.f;
#pragma unroll
  for (int i = 0; i < 4; ++i) { v[i] = __expf(v[i] - mx); sum += v[i]; }
#pragma unroll
  for (int m = 32; m >= 1; m >>= 1) sum += __shfl_xor(sum, m);
  __shared__ float red2[4];
  if ((t & 63) == 0) red2[t >> 6] = sum;
  __syncthreads();
  sum = red2[0] + red2[1] + red2[2] + red2[3];
  float inv = 1.f / sum;
#pragma unroll
  for (int i = 0; i < 4; ++i) wp[(t + 256 * i) * JJ] = v[i] * inv;
}

// ---------------------------------------------------------------- K3: xp = xr*w, LN2 over C, -> bf16
__global__ __launch_bounds__(64) void ln2_xp(const float* __restrict__ xr,
                                             const float* __restrict__ wsm,
                                             const float* __restrict__ g2,
                                             const float* __restrict__ b2,
                                             __hip_bfloat16* __restrict__ xp) {
  int bn = blockIdx.x, lane = threadIdx.x;
  __shared__ float wsh[JJ];
  if (lane < JJ) wsh[lane] = wsm[bn * JJ + lane];
  __syncthreads();
  float vals[9];
  float sum = 0.f;
  for (int it = 0; it < 9; ++it) {
    int c = it * 64 + lane;
    float v = 0.f;
    if (c < CC) v = xr[(size_t)bn * CC + c] * wsh[c >> 5];
    vals[it] = v;
    sum += v;
  }
  for (int m = 32; m >= 1; m >>= 1) sum += __shfl_xor(sum, m);
  float mu = sum * (1.f / 544.f);
  float s2 = 0.f;
  for (int it = 0; it < 9; ++it) {
    int c = it * 64 + lane;
    if (c < CC) { float dv = vals[it] - mu; s2 += dv * dv; }
  }
  for (int m = 32; m >= 1; m >>= 1) s2 += __shfl_xor(s2, m);
  float rstd = rsqrtf(s2 * (1.f / 544.f) + 1e-5f);
  for (int it = 0; it < 9; ++it) {
    int c = it * 64 + lane;
    if (c < CC)
      xp[(size_t)bn * CC + c] = __float2bfloat16((vals[it] - mu) * rstd * g2[c] + b2[c]);
  }
}

// ---------------------------------------------------------------- GEMM: C[M,N] = A[M,K] * B[N,K]^T, bf16 MFMA
// MODE 0: qkv — q->Qp[B,H,N,96], k->Kp[B,H,N,96], v->Vt[B,H,68,1024]
// MODE 1: proj — fp32 + bias to out[8192][544]
template <int MODE>
__global__ __launch_bounds__(256) void gemm_nt(const __hip_bfloat16* __restrict__ A,
                                               const __hip_bfloat16* __restrict__ Bw,
                                               __hip_bfloat16* __restrict__ Qp,
                                               __hip_bfloat16* __restrict__ Kp,
                                               __hip_bfloat16* __restrict__ Vt,
                                               float* __restrict__ Cf,
                                               const float* __restrict__ bias) {
  __shared__ __hip_bfloat16 As[128 * 32];
  __shared__ __hip_bfloat16 Bs[128 * 32];
  const int t = threadIdx.x;
  const int w = t >> 6, lane = t & 63;
  const int fr = lane & 15, fq = lane >> 4;
  const int m0 = blockIdx.x * 128;
  const int n0 = blockIdx.y * 128;
  const int wm = (w >> 1) * 64, wn = (w & 1) * 64;

  f32x4 acc[4][4] = {};

  const __hip_bfloat16* Ag = A + (size_t)m0 * KD;
  const __hip_bfloat16* Bg = Bw + (size_t)n0 * KD;

  for (int kt = 0; kt < 17; ++kt) {
    const int k0 = kt * 32;
#pragma unroll
    for (int i = 0; i < 2; ++i) {
      int cb = (i * 4 + w) * 64;  // wave-uniform chunk base
      int chunk = cb + lane;
      int row = chunk >> 2, c16 = chunk & 3;
      gld_lds16(Ag + (size_t)row * KD + k0 + c16 * 8, &As[cb * 8]);
      gld_lds16(Bg + (size_t)row * KD + k0 + c16 * 8, &Bs[cb * 8]);
    }
    __syncthreads();
    bf16x8 af[4], bfr[4];
#pragma unroll
    for (int tm = 0; tm < 4; ++tm)
      af[tm] = *(const bf16x8*)&As[(wm + tm * 16 + fr) * 32 + fq * 8];
#pragma unroll
    for (int tn = 0; tn < 4; ++tn)
      bfr[tn] = *(const bf16x8*)&Bs[(wn + tn * 16 + fr) * 32 + fq * 8];
#pragma unroll
    for (int tm = 0; tm < 4; ++tm)
#pragma unroll
      for (int tn = 0; tn < 4; ++tn)
        acc[tm][tn] = __builtin_amdgcn_mfma_f32_16x16x32_bf16(af[tm], bfr[tn], acc[tm][tn], 0, 0, 0);
    __syncthreads();
  }

  if (MODE == 1) {
#pragma unroll
    for (int tn = 0; tn < 4; ++tn) {
      int o = n0 + wn + tn * 16 + fr;
      if (o < CC) {
        float bb = bias[o];
#pragma unroll
        for (int tm = 0; tm < 4; ++tm) {
          int m = m0 + wm + tm * 16 + fq * 4;
#pragma unroll
          for (int r = 0; r < 4; ++r)
            Cf[(size_t)(m + r) * CC + o] = acc[tm][tn][r] + bb;
        }
      }
    }
  } else {
    int b = m0 >> 10;
#pragma unroll
    for (int tn = 0; tn < 4; ++tn) {
      int o = n0 + wn + tn * 16 + fr;
      if (o < 2 * CC) {  // q or k -> head-major padded
        int oo = (o < CC) ? o : o - CC;
        int h = oo / HD;
        int d = oo - h * HD;
        __hip_bfloat16* base = (o < CC) ? Qp : Kp;
        __hip_bfloat16* dst = base + ((size_t)(b * HH + h) * NN) * HDP + d;
#pragma unroll
        for (int tm = 0; tm < 4; ++tm) {
          int m = m0 + wm + tm * 16 + fq * 4;
          int n = m & (NN - 1);
#pragma unroll
          for (int r = 0; r < 4; ++r)
            dst[(size_t)(n + r) * HDP] = __float2bfloat16(acc[tm][tn][r]);
        }
      } else if (o < NCQ) {  // v -> transposed
        int oo = o - 2 * CC;
        int h = oo / HD;
        int d = oo - h * HD;
        __hip_bfloat16* vrow = Vt + (((size_t)b * HH + h) * HD + d) * NN;
#pragma unroll
        for (int tm = 0; tm < 4; ++tm) {
          int m = m0 + wm + tm * 16 + fq * 4;
          int n = m & (NN - 1);
#pragma unroll
          for (int r = 0; r < 4; ++r)
            vrow[n + r] = __float2bfloat16(acc[tm][tn][r]);
        }
      }
    }
  }
}

// ---------------------------------------------------------------- Flash attention, bf16 MFMA
// grid (16 qtiles, H, B), 256 threads = 4 waves x 16 q-rows
// Q/K tiles: contiguous 12KB from Qp/Kp via global_load_lds width=16
__global__ __launch_bounds__(256) void attn_kernel(const __hip_bfloat16* __restrict__ Qp,
                                                   const __hip_bfloat16* __restrict__ Kp,
                                                   const __hip_bfloat16* __restrict__ Vt,
                                                   const float* __restrict__ sfp,
                                                   __hip_bfloat16* __restrict__ Ao) {
  __shared__ __hip_bfloat16 Qs[64 * HDP];   // 12288 B, contiguous with global layout
  __shared__ __hip_bfloat16 Ks[64 * HDP];   // 12288 B
  __shared__ __hip_bfloat16 Vs[80][72];     // V^T: d-rows x 64 keys, stride 72 (bank-balanced)
  __shared__ __hip_bfloat16 Ps[4][16][72];  // per-wave P round-trip (C-layout -> A-layout)
  const int t = threadIdx.x;
  const int w = t >> 6, lane = t & 63;
  const int fr = lane & 15, fq = lane >> 4;
  const int qt = blockIdx.x, h = blockIdx.y, b = blockIdx.z;
  const float sf = sfp[0];
  const float scale = 0.12126781251816650f;  // 68^-0.5

  const __hip_bfloat16* qtile = Qp + ((size_t)(b * HH + h) * NN + qt * 64) * HDP;
#pragma unroll
  for (int i = 0; i < 3; ++i) {
    int cb = (i * 4 + w) * 64;  // wave-uniform 16B-slot base
    gld_lds16(qtile + (size_t)(cb + lane) * 8, &Qs[cb * 8]);
  }
  __syncthreads();
  bf16x8 qa[3];
#pragma unroll
  for (int ks = 0; ks < 3; ++ks)
    qa[ks] = *(const bf16x8*)&Qs[(w * 16 + fr) * HDP + ks * 32 + fq * 8];

  f32x4 o_acc[5] = {};
  float m_i[4], l_i[4];
#pragma unroll
  for (int r = 0; r < 4; ++r) { m_i[r] = -1e30f; l_i[r] = 0.f; }

  const __hip_bfloat16* kbase = Kp + (size_t)(b * HH + h) * NN * HDP;
  const __hip_bfloat16* vbase = Vt + ((size_t)b * HH + h) * HD * NN;

  for (int kt = 0; kt < 16; ++kt) {
    __syncthreads();  // all waves done reading previous K/V tiles
    const __hip_bfloat16* ktile = kbase + (size_t)kt * 64 * HDP;
#pragma unroll
    for (int i = 0; i < 3; ++i) {
      int cb = (i * 4 + w) * 64;
      gld_lds16(ktile + (size_t)(cb + lane) * 8, &Ks[cb * 8]);
    }
    // V^T: 68 rows x 64 keys, uint4 copies (8 per row)
    for (int task = t; task < 68 * 8; task += 256) {
      int d = task >> 3, i = task & 7;
      *(uint4*)&Vs[d][i * 8] = *(const uint4*)(vbase + (size_t)d * NN + kt * 64 + i * 8);
    }
    __syncthreads();

    // S = Q K^T  (16q x 64k per wave)
    f32x4 s[4] = {};
#pragma unroll
    for (int tn = 0; tn < 4; ++tn) {
#pragma unroll
      for (int ks = 0; ks < 3; ++ks) {
        bf16x8 kb = *(const bf16x8*)&Ks[(tn * 16 + fr) * HDP + ks * 32 + fq * 8];
        s[tn] = __builtin_amdgcn_mfma_f32_16x16x32_bf16(qa[ks], kb, s[tn], 0, 0, 0);
      }
    }
    // logit scaling: scale * pos_scale[key]
#pragma unroll
    for (int tn = 0; tn < 4; ++tn) {
      int key = kt * 64 + tn * 16 + fr;
      float pos = key * (1.f / 1023.f) - 0.5f;
      float ps = __expf(-sf * pos * pos) * scale;
#pragma unroll
      for (int r = 0; r < 4; ++r) s[tn][r] *= ps;
    }
    // online softmax (rows = fq*4+r, cols across fr within quad)
    float alpha[4];
#pragma unroll
    for (int r = 0; r < 4; ++r) {
      float mx = fmaxf(fmaxf(s[0][r], s[1][r]), fmaxf(s[2][r], s[3][r]));
#pragma unroll
      for (int msk = 8; msk >= 1; msk >>= 1) mx = fmaxf(mx, __shfl_xor(mx, msk));
      float mn = fmaxf(m_i[r], mx);
      alpha[r] = __expf(m_i[r] - mn);
      m_i[r] = mn;
      float rs = 0.f;
#pragma unroll
      for (int tn = 0; tn < 4; ++tn) {
        float p = __expf(s[tn][r] - mn);
        s[tn][r] = p;
        rs += p;
      }
#pragma unroll
      for (int msk = 8; msk >= 1; msk >>= 1) rs += __shfl_xor(rs, msk);
      l_i[r] = l_i[r] * alpha[r] + rs;
#pragma unroll
      for (int tv = 0; tv < 5; ++tv) o_acc[tv][r] *= alpha[r];
    }
    // P: C-layout -> LDS -> A-layout
#pragma unroll
    for (int tn = 0; tn < 4; ++tn)
#pragma unroll
      for (int r = 0; r < 4; ++r)
        Ps[w][fq * 4 + r][tn * 16 + fr] = __float2bfloat16(s[tn][r]);
    // O += P V   (rows 68..79 of Vs are unstaged garbage -> discarded outputs only)
#pragma unroll
    for (int ks2 = 0; ks2 < 2; ++ks2) {
      bf16x8 pa = *(const bf16x8*)&Ps[w][fr][ks2 * 32 + fq * 8];
#pragma unroll
      for (int tv = 0; tv < 5; ++tv) {
        bf16x8 vb = *(const bf16x8*)&Vs[tv * 16 + fr][ks2 * 32 + fq * 8];
        o_acc[tv] = __builtin_amdgcn_mfma_f32_16x16x32_bf16(pa, vb, o_acc[tv], 0, 0, 0);
      }
    }
  }
  // epilogue: O / l -> bf16 attn_out[m][h*68+d]
  __hip_bfloat16* obase = Ao + (size_t)(b * NN + qt * 64 + w * 16) * CC + h * HD;
  float inv[4];
#pragma unroll
  for (int r = 0; r < 4; ++r) inv[r] = 1.f / l_i[r];
#pragma unroll
  for (int tv = 0; tv < 5; ++tv) {
    int d = tv * 16 + fr;
    if (d < HD) {
#pragma unroll
      for (int r = 0; r < 4; ++r)
        obase[(size_t)(fq * 4 + r) * CC + d] = __float2bfloat16(o_acc[tv][r] * inv[r]);
    }
  }
}

// ---------------------------------------------------------------- launch
extern "C" void kernel_launch(void* const* d_in, const int* in_sizes, int n_in,
                              void* d_out, int out_size, void* d_ws, size_t ws_size,
                              hipStream_t stream) {
  (void)in_sizes; (void)n_in; (void)out_size; (void)ws_size;
  const float* x       = (const float*)d_in[0];
  const float* norm_g  = (const float*)d_in[1];
  const float* norm_b  = (const float*)d_in[2];
  const float* ap_w    = (const float*)d_in[3];
  const float* ap_b    = (const float*)d_in[4];
  const float* norm2_g = (const float*)d_in[5];
  const float* norm2_b = (const float*)d_in[6];
  const float* qkv_w   = (const float*)d_in[7];
  const float* proj_w  = (const float*)d_in[8];
  const float* proj_b  = (const float*)d_in[9];
  const float* sf      = (const float*)d_in[10];
  float* out = (float*)d_out;
  char* ws = (char*)d_ws;

  // workspace layout (bytes)
  float* xr              = (float*)(ws);                       // 8192*544*4  = 17825792
  float* scores          = (float*)(ws + 17825792);            // 8192*17*4   = 557056
  float* wsm             = (float*)(ws + 18382848);            // 557056
  __hip_bfloat16* xp     = (__hip_bfloat16*)(ws + 18939904);   // 8192*544*2  = 8912896
  __hip_bfloat16* qw     = (__hip_bfloat16*)(ws + 27852800);   // 1664*544*2  = 1810432
  __hip_bfloat16* pw     = (__hip_bfloat16*)(ws + 29663232);   // 640*544*2   = 696320
  __hip_bfloat16* vt     = (__hip_bfloat16*)(ws + 30359552);   // 8*8*68*1024*2 = 8912896
  __hip_bfloat16* ao     = (__hip_bfloat16*)(ws + 39272448);   // 8192*544*2  = 8912896
  __hip_bfloat16* qp     = (__hip_bfloat16*)(ws + 48185344);   // 8*8*1024*96*2 = 12582912
  __hip_bfloat16* kp     = (__hip_bfloat16*)(ws + 60768256);   // 12582912
  // total 73351168 bytes

  wconv<<<4896, 256, 0, stream>>>(qkv_w, proj_w, qw, pw);
  zero_qk_pad<<<3584, 256, 0, stream>>>((char*)qp);
  ln1_scores<<<BN, 64, 0, stream>>>(x, norm_g, norm_b, ap_w, ap_b, xr, scores);
  softmax_n<<<BB * JJ, 256, 0, stream>>>(scores, wsm);
  ln2_xp<<<BN, 64, 0, stream>>>(xr, wsm, norm2_g, norm2_b, xp);
  gemm_nt<0><<<dim3(64, 13), 256, 0, stream>>>(xp, qw, qp, kp, vt, nullptr, nullptr);
  attn_kernel<<<dim3(16, HH, BB), 256, 0, stream>>>(qp, kp, vt, sf, ao);
  gemm_nt<1><<<dim3(64, 5), 256, 0, stream>>>(ao, pw, nullptr, nullptr, nullptr, out, proj_b);
}

// Round 4
// 250.467 us; speedup vs baseline: 2.3832x; 1.0767x over previous
//
#include <hip/hip_runtime.h>
#include <hip/hip_bf16.h>

// Problem constants
#define BB 8
#define NN 1024
#define CC 544      // J*F = 17*32
#define JJ 17
#define FF 32
#define HH 8
#define HD 68
#define BN 8192     // B*N
#define KD 544      // GEMM K dim (=C)
#define NCQ 1632    // 3*C
#define NCQP 1664   // padded to 13*128
#define NCPP 640    // proj out padded to 5*128
#define HDP 96      // head dim padded for QK (3x K=32)
#define QROWS 128   // q-rows per attention block (4 waves x 2 groups x 16)

using f32x4  = __attribute__((ext_vector_type(4))) float;
using bf16x8 = __attribute__((ext_vector_type(8))) short;

__device__ __forceinline__ void gld_lds16(const void* g, void* l) {
  __builtin_amdgcn_global_load_lds(
      (const __attribute__((address_space(1))) void*)g,
      (__attribute__((address_space(3))) void*)l, 16, 0, 0);
}

// ---------------------------------------------------------------- K0: weights -> bf16 (padded)
__global__ __launch_bounds__(256) void wconv(const float* __restrict__ qkv_w,
                                             const float* __restrict__ proj_w,
                                             __hip_bfloat16* __restrict__ qw,
                                             __hip_bfloat16* __restrict__ pw) {
  int idx = blockIdx.x * 256 + threadIdx.x;
  const int t1 = NCQP * KD;
  if (idx < t1) {
    int r = idx / KD;
    qw[idx] = __float2bfloat16(r < NCQ ? qkv_w[idx] : 0.f);
  } else {
    int k = idx - t1;
    if (k < NCPP * KD) {
      int r = k / KD;
      pw[k] = __float2bfloat16(r < CC ? proj_w[k] : 0.f);
    }
  }
}

// ---------------------------------------------------------------- K0b: zero pad cols 68..95 of Qp||Kp
__global__ __launch_bounds__(256) void zero_qk_pad(char* __restrict__ qkp) {
  int t = blockIdx.x * 256 + threadIdx.x;  // 131072*7 = 917504 tasks
  if (t < 131072 * 7) {
    int row = t / 7, i = t - row * 7;
    *(unsigned long long*)(qkp + (size_t)row * 192 + 136 + i * 8) = 0ull;
  }
}

// ---------------------------------------------------------------- K1: per-joint LN + attention-pool scores
__global__ __launch_bounds__(64) void ln1_scores(const float* __restrict__ x,
                                                 const float* __restrict__ g,
                                                 const float* __restrict__ bta,
                                                 const float* __restrict__ apw,
                                                 const float* __restrict__ apb,
                                                 float* __restrict__ xr,
                                                 float* __restrict__ scores) {
  int bn = blockIdx.x, lane = threadIdx.x;
  int f = lane & 31, half = lane >> 5;
  const float* row = x + (size_t)bn * CC;
  float gg = g[f], bb = bta[f], aw = apw[f], ab = apb[0];
  for (int it = 0; it < 9; ++it) {
    int j = it * 2 + half;
    bool act = (j < JJ);
    float v = act ? row[j * FF + f] : 0.f;
    float s = v;
    for (int m = 16; m >= 1; m >>= 1) s += __shfl_xor(s, m);
    float mu = s * (1.f / 32.f);
    float dv = v - mu;
    float s2 = dv * dv;
    for (int m = 16; m >= 1; m >>= 1) s2 += __shfl_xor(s2, m);
    float xn = dv * rsqrtf(s2 * (1.f / 32.f) + 1e-5f) * gg + bb;
    float sc = xn * aw;
    for (int m = 16; m >= 1; m >>= 1) sc += __shfl_xor(sc, m);
    if (act) {
      xr[(size_t)bn * CC + j * FF + f] = xn;
      if (f == 0) scores[bn * JJ + j] = sc + ab;
    }
  }
}

// ---------------------------------------------------------------- K2: softmax over sequence axis N per (b,j)
__global__ __launch_bounds__(256) void softmax_n(const float* __restrict__ scores,
                                                 float* __restrict__ wsm) {
  int bj = blockIdx.x;
  int b = bj / JJ, j = bj - b * JJ;
  const float* s = scores + (size_t)b * NN * JJ + j;
  float* wp = wsm + (size_t)b * NN * JJ + j;
  int t = threadIdx.x;
  float v[4];
  float mx = -1e30f;
#pragma unroll
  for (int i = 0; i < 4; ++i) { v[i] = s[(t + 256 * i) * JJ]; mx = fmaxf(mx, v[i]); }
#pragma unroll
  for (int m = 32; m >= 1; m >>= 1) mx = fmaxf(mx, __shfl_xor(mx, m));
  __shared__ float red[4];
  if ((t & 63) == 0) red[t >> 6] = mx;
  __syncthreads();
  mx = fmaxf(fmaxf(red[0], red[1]), fmaxf(red[2], red[3]));
  float sum = 0.f;
#pragma unroll
  for (int i = 0; i < 4; ++i) { v[i] = __expf(v[i] - mx); sum += v[i]; }
#pragma unroll
  for (int m = 32; m >= 1; m >>= 1) sum += __shfl_xor(sum, m);
  __shared__ float red2[4];
  if ((t & 63) == 0) red2[t >> 6] = sum;
  __syncthreads();
  sum = red2[0] + red2[1] + red2[2] + red2[3];
  float inv = 1.f / sum;
#pragma unroll
  for (int i = 0; i < 4; ++i) wp[(t + 256 * i) * JJ] = v[i] * inv;
}

// ---------------------------------------------------------------- K3: xp = xr*w, LN2 over C, -> bf16
__global__ __launch_bounds__(64) void ln2_xp(const float* __restrict__ xr,
                                             const float* __restrict__ wsm,
                                             const float* __restrict__ g2,
                                             const float* __restrict__ b2,
                                             __hip_bfloat16* __restrict__ xp) {
  int bn = blockIdx.x, lane = threadIdx.x;
  __shared__ float wsh[JJ];
  if (lane < JJ) wsh[lane] = wsm[bn * JJ + lane];
  __syncthreads();
  float vals[9];
  float sum = 0.f;
  for (int it = 0; it < 9; ++it) {
    int c = it * 64 + lane;
    float v = 0.f;
    if (c < CC) v = xr[(size_t)bn * CC + c] * wsh[c >> 5];
    vals[it] = v;
    sum += v;
  }
  for (int m = 32; m >= 1; m >>= 1) sum += __shfl_xor(sum, m);
  float mu = sum * (1.f / 544.f);
  float s2 = 0.f;
  for (int it = 0; it < 9; ++it) {
    int c = it * 64 + lane;
    if (c < CC) { float dv = vals[it] - mu; s2 += dv * dv; }
  }
  for (int m = 32; m >= 1; m >>= 1) s2 += __shfl_xor(s2, m);
  float rstd = rsqrtf(s2 * (1.f / 544.f) + 1e-5f);
  for (int it = 0; it < 9; ++it) {
    int c = it * 64 + lane;
    if (c < CC)
      xp[(size_t)bn * CC + c] = __float2bfloat16((vals[it] - mu) * rstd * g2[c] + b2[c]);
  }
}

// ---------------------------------------------------------------- GEMM: C[M,N] = A[M,K] * B[N,K]^T, bf16 MFMA
// MODE 0: qkv — q->Qp[B,H,N,96], k->Kp[B,H,N,96] PRE-SCALED by scale*pos_scale[n], v->Vt[B,H,68,1024]
// MODE 1: proj — fp32 + bias to out[8192][544]
template <int MODE>
__global__ __launch_bounds__(256) void gemm_nt(const __hip_bfloat16* __restrict__ A,
                                               const __hip_bfloat16* __restrict__ Bw,
                                               __hip_bfloat16* __restrict__ Qp,
                                               __hip_bfloat16* __restrict__ Kp,
                                               __hip_bfloat16* __restrict__ Vt,
                                               float* __restrict__ Cf,
                                               const float* __restrict__ bias,
                                               const float* __restrict__ sfp) {
  __shared__ __hip_bfloat16 As[128 * 32];
  __shared__ __hip_bfloat16 Bs[128 * 32];
  const int t = threadIdx.x;
  const int w = t >> 6, lane = t & 63;
  const int fr = lane & 15, fq = lane >> 4;
  const int m0 = blockIdx.x * 128;
  const int n0 = blockIdx.y * 128;
  const int wm = (w >> 1) * 64, wn = (w & 1) * 64;

  f32x4 acc[4][4] = {};

  const __hip_bfloat16* Ag = A + (size_t)m0 * KD;
  const __hip_bfloat16* Bg = Bw + (size_t)n0 * KD;

  for (int kt = 0; kt < 17; ++kt) {
    const int k0 = kt * 32;
#pragma unroll
    for (int i = 0; i < 2; ++i) {
      int cb = (i * 4 + w) * 64;  // wave-uniform chunk base
      int chunk = cb + lane;
      int row = chunk >> 2, c16 = chunk & 3;
      gld_lds16(Ag + (size_t)row * KD + k0 + c16 * 8, &As[cb * 8]);
      gld_lds16(Bg + (size_t)row * KD + k0 + c16 * 8, &Bs[cb * 8]);
    }
    __syncthreads();
    bf16x8 af[4], bfr[4];
#pragma unroll
    for (int tm = 0; tm < 4; ++tm)
      af[tm] = *(const bf16x8*)&As[(wm + tm * 16 + fr) * 32 + fq * 8];
#pragma unroll
    for (int tn = 0; tn < 4; ++tn)
      bfr[tn] = *(const bf16x8*)&Bs[(wn + tn * 16 + fr) * 32 + fq * 8];
#pragma unroll
    for (int tm = 0; tm < 4; ++tm)
#pragma unroll
      for (int tn = 0; tn < 4; ++tn)
        acc[tm][tn] = __builtin_amdgcn_mfma_f32_16x16x32_bf16(af[tm], bfr[tn], acc[tm][tn], 0, 0, 0);
    __syncthreads();
  }

  if (MODE == 1) {
#pragma unroll
    for (int tn = 0; tn < 4; ++tn) {
      int o = n0 + wn + tn * 16 + fr;
      if (o < CC) {
        float bb = bias[o];
#pragma unroll
        for (int tm = 0; tm < 4; ++tm) {
          int m = m0 + wm + tm * 16 + fq * 4;
#pragma unroll
          for (int r = 0; r < 4; ++r)
            Cf[(size_t)(m + r) * CC + o] = acc[tm][tn][r] + bb;
        }
      }
    }
  } else {
    int b = m0 >> 10;
    float sf = sfp[0];
#pragma unroll
    for (int tn = 0; tn < 4; ++tn) {
      int o = n0 + wn + tn * 16 + fr;
      if (o < 2 * CC) {  // q or k -> head-major padded
        bool is_k = (o >= CC);
        int oo = is_k ? o - CC : o;
        int h = oo / HD;
        int d = oo - h * HD;
        __hip_bfloat16* base = is_k ? Kp : Qp;
        __hip_bfloat16* dst = base + ((size_t)(b * HH + h) * NN) * HDP + d;
#pragma unroll
        for (int tm = 0; tm < 4; ++tm) {
          int m = m0 + wm + tm * 16 + fq * 4;
          int n = m & (NN - 1);
#pragma unroll
          for (int r = 0; r < 4; ++r) {
            float v = acc[tm][tn][r];
            if (is_k) {
              // fold softmax scale * per-key positional scale into K
              float pos = (n + r) * (1.f / 1023.f) - 0.5f;
              v *= __expf(-sf * pos * pos) * 0.12126781251816650f;  // 68^-0.5
            }
            dst[(size_t)(n + r) * HDP] = __float2bfloat16(v);
          }
        }
      } else if (o < NCQ) {  // v -> transposed
        int oo = o - 2 * CC;
        int h = oo / HD;
        int d = oo - h * HD;
        __hip_bfloat16* vrow = Vt + (((size_t)b * HH + h) * HD + d) * NN;
#pragma unroll
        for (int tm = 0; tm < 4; ++tm) {
          int m = m0 + wm + tm * 16 + fq * 4;
          int n = m & (NN - 1);
#pragma unroll
          for (int r = 0; r < 4; ++r)
            vrow[n + r] = __float2bfloat16(acc[tm][tn][r]);
        }
      }
    }
  }
}

// ---------------------------------------------------------------- Flash attention, bf16 MFMA
// grid (8 qtiles, H, B), 256 threads = 4 waves, each wave owns 2x16 q-rows (128 rows/block).
// Qs (24KB) is reused as per-wave Ps scratch after Q fragments are register-resident.
// Logits come out of QK^T pre-scaled (K folded with scale*pos_scale).
__global__ __launch_bounds__(256) void attn_kernel(const __hip_bfloat16* __restrict__ Qp,
                                                   const __hip_bfloat16* __restrict__ Kp,
                                                   const __hip_bfloat16* __restrict__ Vt,
                                                   __hip_bfloat16* __restrict__ Ao) {
  __shared__ __hip_bfloat16 Qs[QROWS * HDP];  // 24576B; reused as Ps[8][16][72] (18432B)
  __shared__ __hip_bfloat16 Ks[64 * HDP];     // 12288B
  __shared__ __hip_bfloat16 Vs[80][72];       // 11520B, V^T d-rows x 64 keys
  const int t = threadIdx.x;
  const int w = t >> 6, lane = t & 63;
  const int fr = lane & 15, fq = lane >> 4;
  const int qt = blockIdx.x, h = blockIdx.y, b = blockIdx.z;

  const __hip_bfloat16* qtile = Qp + ((size_t)(b * HH + h) * NN + qt * QROWS) * HDP;
#pragma unroll
  for (int i = 0; i < 6; ++i) {
    int cb = (i * 4 + w) * 64;  // wave-uniform 16B-slot base
    gld_lds16(qtile + (size_t)(cb + lane) * 8, &Qs[cb * 8]);
  }
  __syncthreads();
  bf16x8 qa[2][3];
#pragma unroll
  for (int g = 0; g < 2; ++g)
#pragma unroll
    for (int ks = 0; ks < 3; ++ks)
      qa[g][ks] = *(const bf16x8*)&Qs[(w * 32 + g * 16 + fr) * HDP + ks * 32 + fq * 8];

  f32x4 o_acc[2][5] = {};
  float m_i[2][4], l_i[2][4];
#pragma unroll
  for (int g = 0; g < 2; ++g)
#pragma unroll
    for (int r = 0; r < 4; ++r) { m_i[g][r] = -1e30f; l_i[g][r] = 0.f; }

  const __hip_bfloat16* kbase = Kp + (size_t)(b * HH + h) * NN * HDP;
  const __hip_bfloat16* vbase = Vt + ((size_t)b * HH + h) * HD * NN;

  for (int kt = 0; kt < 16; ++kt) {
    __syncthreads();  // all waves done with previous Ks/Vs (and, on kt=0, qa reads)
    const __hip_bfloat16* ktile = kbase + (size_t)kt * 64 * HDP;
#pragma unroll
    for (int i = 0; i < 3; ++i) {
      int cb = (i * 4 + w) * 64;
      gld_lds16(ktile + (size_t)(cb + lane) * 8, &Ks[cb * 8]);
    }
    for (int task = t; task < 68 * 8; task += 256) {
      int d = task >> 3, i = task & 7;
      *(uint4*)&Vs[d][i * 8] = *(const uint4*)(vbase + (size_t)d * NN + kt * 64 + i * 8);
    }
    __syncthreads();

    // S = Q K^T for both row-groups; each K fragment load feeds 2 MFMAs
    f32x4 s[2][4] = {};
#pragma unroll
    for (int tn = 0; tn < 4; ++tn) {
#pragma unroll
      for (int ks = 0; ks < 3; ++ks) {
        bf16x8 kb = *(const bf16x8*)&Ks[(tn * 16 + fr) * HDP + ks * 32 + fq * 8];
        s[0][tn] = __builtin_amdgcn_mfma_f32_16x16x32_bf16(qa[0][ks], kb, s[0][tn], 0, 0, 0);
        s[1][tn] = __builtin_amdgcn_mfma_f32_16x16x32_bf16(qa[1][ks], kb, s[1][tn], 0, 0, 0);
      }
    }
    // online softmax per group (logits already scaled)
#pragma unroll
    for (int g = 0; g < 2; ++g) {
      __hip_bfloat16(*Ps)[72] = (__hip_bfloat16(*)[72])&Qs[(w * 2 + g) * 1152];
#pragma unroll
      for (int r = 0; r < 4; ++r) {
        float mx = fmaxf(fmaxf(s[g][0][r], s[g][1][r]), fmaxf(s[g][2][r], s[g][3][r]));
#pragma unroll
        for (int msk = 8; msk >= 1; msk >>= 1) mx = fmaxf(mx, __shfl_xor(mx, msk));
        float mn = fmaxf(m_i[g][r], mx);
        float alpha = __expf(m_i[g][r] - mn);
        m_i[g][r] = mn;
        float rs = 0.f;
#pragma unroll
        for (int tn = 0; tn < 4; ++tn) {
          float p = __expf(s[g][tn][r] - mn);
          s[g][tn][r] = p;
          rs += p;
        }
#pragma unroll
        for (int msk = 8; msk >= 1; msk >>= 1) rs += __shfl_xor(rs, msk);
        l_i[g][r] = l_i[g][r] * alpha + rs;
#pragma unroll
        for (int tv = 0; tv < 5; ++tv) o_acc[g][tv][r] *= alpha;
      }
      // P: C-layout -> LDS (per-wave region inside dead Qs)
#pragma unroll
      for (int tn = 0; tn < 4; ++tn)
#pragma unroll
        for (int r = 0; r < 4; ++r)
          Ps[fq * 4 + r][tn * 16 + fr] = __float2bfloat16(s[g][tn][r]);
    }
    // O += P V; each V fragment load feeds 2 MFMAs (rows 68..79 of Vs garbage -> discarded cols)
#pragma unroll
    for (int ks2 = 0; ks2 < 2; ++ks2) {
      bf16x8 pa0 = *(const bf16x8*)&Qs[(w * 2 + 0) * 1152 + fr * 72 + ks2 * 32 + fq * 8];
      bf16x8 pa1 = *(const bf16x8*)&Qs[(w * 2 + 1) * 1152 + fr * 72 + ks2 * 32 + fq * 8];
#pragma unroll
      for (int tv = 0; tv < 5; ++tv) {
        bf16x8 vb = *(const bf16x8*)&Vs[tv * 16 + fr][ks2 * 32 + fq * 8];
        o_acc[0][tv] = __builtin_amdgcn_mfma_f32_16x16x32_bf16(pa0, vb, o_acc[0][tv], 0, 0, 0);
        o_acc[1][tv] = __builtin_amdgcn_mfma_f32_16x16x32_bf16(pa1, vb, o_acc[1][tv], 0, 0, 0);
      }
    }
  }
  // epilogue: O / l -> bf16 attn_out[m][h*68+d]
#pragma unroll
  for (int g = 0; g < 2; ++g) {
    __hip_bfloat16* obase = Ao + (size_t)(b * NN + qt * QROWS + w * 32 + g * 16) * CC + h * HD;
    float inv[4];
#pragma unroll
    for (int r = 0; r < 4; ++r) inv[r] = 1.f / l_i[g][r];
#pragma unroll
    for (int tv = 0; tv < 5; ++tv) {
      int d = tv * 16 + fr;
      if (d < HD) {
#pragma unroll
        for (int r = 0; r < 4; ++r)
          obase[(size_t)(fq * 4 + r) * CC + d] = __float2bfloat16(o_acc[g][tv][r] * inv[r]);
      }
    }
  }
}

// ---------------------------------------------------------------- launch
extern "C" void kernel_launch(void* const* d_in, const int* in_sizes, int n_in,
                              void* d_out, int out_size, void* d_ws, size_t ws_size,
                              hipStream_t stream) {
  (void)in_sizes; (void)n_in; (void)out_size; (void)ws_size;
  const float* x       = (const float*)d_in[0];
  const float* norm_g  = (const float*)d_in[1];
  const float* norm_b  = (const float*)d_in[2];
  const float* ap_w    = (const float*)d_in[3];
  const float* ap_b    = (const float*)d_in[4];
  const float* norm2_g = (const float*)d_in[5];
  const float* norm2_b = (const float*)d_in[6];
  const float* qkv_w   = (const float*)d_in[7];
  const float* proj_w  = (const float*)d_in[8];
  const float* proj_b  = (const float*)d_in[9];
  const float* sf      = (const float*)d_in[10];
  float* out = (float*)d_out;
  char* ws = (char*)d_ws;

  // workspace layout (bytes)
  float* xr              = (float*)(ws);                       // 8192*544*4  = 17825792
  float* scores          = (float*)(ws + 17825792);            // 8192*17*4   = 557056
  float* wsm             = (float*)(ws + 18382848);            // 557056
  __hip_bfloat16* xp     = (__hip_bfloat16*)(ws + 18939904);   // 8192*544*2  = 8912896
  __hip_bfloat16* qw     = (__hip_bfloat16*)(ws + 27852800);   // 1664*544*2  = 1810432
  __hip_bfloat16* pw     = (__hip_bfloat16*)(ws + 29663232);   // 640*544*2   = 696320
  __hip_bfloat16* vt     = (__hip_bfloat16*)(ws + 30359552);   // 8*8*68*1024*2 = 8912896
  __hip_bfloat16* ao     = (__hip_bfloat16*)(ws + 39272448);   // 8192*544*2  = 8912896
  __hip_bfloat16* qp     = (__hip_bfloat16*)(ws + 48185344);   // 8*8*1024*96*2 = 12582912
  __hip_bfloat16* kp     = (__hip_bfloat16*)(ws + 60768256);   // 12582912
  // total 73351168 bytes

  wconv<<<4896, 256, 0, stream>>>(qkv_w, proj_w, qw, pw);
  zero_qk_pad<<<3584, 256, 0, stream>>>((char*)qp);
  ln1_scores<<<BN, 64, 0, stream>>>(x, norm_g, norm_b, ap_w, ap_b, xr, scores);
  softmax_n<<<BB * JJ, 256, 0, stream>>>(scores, wsm);
  ln2_xp<<<BN, 64, 0, stream>>>(xr, wsm, norm2_g, norm2_b, xp);
  gemm_nt<0><<<dim3(64, 13), 256, 0, stream>>>(xp, qw, qp, kp, vt, nullptr, nullptr, sf);
  attn_kernel<<<dim3(NN / QROWS, HH, BB), 256, 0, stream>>>(qp, kp, vt, ao);
  gemm_nt<1><<<dim3(64, 5), 256, 0, stream>>>(ao, pw, nullptr, nullptr, nullptr, out, proj_b, nullptr);
}